// Round 1
// baseline (110.891 us; speedup 1.0000x reference)
//
#include <hip/hip_runtime.h>

// VQ-VAE vector quantizer, MI355X gfx950.
// z: [16,64,64,64] fp32, embed: [1024,64] fp32.
// out: z_q (=z_q_st numerically) [16,64,64,64] fp32, then loss scalar.
//
// Strategy: distances via bf16 MFMA (16x16x32), argmin fused, exact-fp32
// epilogue (codebook gather, scatter to NCHW, loss reduction).

#define K_CODES   1024
#define C_DIM     64
#define HW        4096
#define CHW       262144
#define OUT_ELEMS 4194304
#define LOSS_SCALE (1.25f / 4194304.0f)
#define ZPAD      68   // floats per LDS row (64 + 4 pad, keeps float4 alignment)

typedef short v8s __attribute__((ext_vector_type(8)));
typedef float v4f __attribute__((ext_vector_type(4)));

__device__ __forceinline__ unsigned short f2bf(float x) {
  // round-to-nearest-even fp32 -> bf16 (inputs finite)
  unsigned int u = __float_as_uint(x);
  return (unsigned short)((u + 0x7FFFu + ((u >> 16) & 1u)) >> 16);
}

// ---------------------------------------------------------------------------
// Setup kernel: 32 blocks x 256 threads (8192 threads).
//  - packs embed into bf16 B-fragment order: for code-tile t (16 codes),
//    k-half h, lane l (col=l&15,q=l>>4): 16B chunk = embed[t*16+col][h*32+q*8 ..+7]
//    stored at ws_frag[t*128 + h*64 + l]  -> main-loop loads are coalesced.
//  - threads 0..1023: ws_norm[k] = ||embed[k]||^2 in fp32.
//  - thread 0: zero the loss accumulator (d_out is poisoned 0xAA pre-launch).
// ---------------------------------------------------------------------------
__global__ __launch_bounds__(256) void vq_setup(const float* __restrict__ embed,
                                                float* __restrict__ ws_norm,
                                                uint4* __restrict__ ws_frag,
                                                float* __restrict__ out_loss) {
  int id = blockIdx.x * 256 + threadIdx.x;   // 0..8191
  int t   = id >> 7;        // code tile 0..63
  int r   = id & 127;
  int h   = r >> 6;         // k-half 0..1
  int l   = r & 63;         // lane
  int col = l & 15;
  int q   = l >> 4;
  int code = t * 16 + col;
  const float* src = embed + code * C_DIM + h * 32 + q * 8;
  float4 f0 = ((const float4*)src)[0];
  float4 f1 = ((const float4*)src)[1];
  union { unsigned short u[8]; uint4 q4; } pk;
  pk.u[0] = f2bf(f0.x); pk.u[1] = f2bf(f0.y); pk.u[2] = f2bf(f0.z); pk.u[3] = f2bf(f0.w);
  pk.u[4] = f2bf(f1.x); pk.u[5] = f2bf(f1.y); pk.u[6] = f2bf(f1.z); pk.u[7] = f2bf(f1.w);
  ws_frag[id] = pk.q4;

  if (id < K_CODES) {
    const float4* row = (const float4*)(embed + id * C_DIM);
    float s = 0.f;
#pragma unroll
    for (int i = 0; i < 16; ++i) {
      float4 v = row[i];
      s += v.x * v.x + v.y * v.y + v.z * v.z + v.w * v.w;
    }
    ws_norm[id] = s;
  }
  if (id == 0) *out_loss = 0.f;
}

// ---------------------------------------------------------------------------
// Main kernel: 256 blocks x 256 threads. Block = 256 consecutive positions
// (b = blk>>4, h in [h0,h0+4), all 64 w). Wave owns 64 positions.
// ---------------------------------------------------------------------------
__global__ __launch_bounds__(256, 1) void vq_main(const float* __restrict__ z,
                                                  const float* __restrict__ embed,
                                                  const float* __restrict__ ws_norm,
                                                  const uint4* __restrict__ ws_frag,
                                                  float* __restrict__ out) {
  __shared__ float z_lds[256 * ZPAD];   // 69632 B, [pos][ch] fp32
  __shared__ int   idx_lds[256];
  __shared__ float wl[4];

  const int tid = threadIdx.x;
  const int b   = blockIdx.x >> 4;
  const int h0  = (blockIdx.x & 15) << 2;

  // ---- stage z tile: global (coalesced over w) -> LDS [pos][c] ----
  {
    const int w  = tid & 63;
    const int c0 = tid >> 6;
    const float* zb = z + b * CHW + h0 * 64 + w;
    for (int c = c0; c < C_DIM; c += 4) {
      const float* zc = zb + c * HW;
#pragma unroll
      for (int hh = 0; hh < 4; ++hh)
        z_lds[(hh * 64 + w) * ZPAD + c] = zc[hh * 64];
    }
  }
  __syncthreads();

  const int lane = tid & 63;
  const int wave = tid >> 6;
  const int col  = lane & 15;
  const int q    = lane >> 4;

  // ---- build A-frags (z as bf16), held in registers for the whole K loop ----
  // A layout: lane m=lane&15 holds A[m][q*8+j] (k-half hf adds 32).
  v8s afrag[4][2];
#pragma unroll
  for (int g = 0; g < 4; ++g) {
    int pos = wave * 64 + g * 16 + col;
#pragma unroll
    for (int hf = 0; hf < 2; ++hf) {
      const float* srcp = &z_lds[pos * ZPAD + hf * 32 + q * 8];
      float4 f0 = ((const float4*)srcp)[0];
      float4 f1 = ((const float4*)srcp)[1];
      union { v8s v; unsigned short u[8]; } pk;
      pk.u[0] = f2bf(f0.x); pk.u[1] = f2bf(f0.y); pk.u[2] = f2bf(f0.z); pk.u[3] = f2bf(f0.w);
      pk.u[4] = f2bf(f1.x); pk.u[5] = f2bf(f1.y); pk.u[6] = f2bf(f1.z); pk.u[7] = f2bf(f1.w);
      afrag[g][hf] = pk.v;
    }
  }

  float minv[4][4];
  int   mini[4][4];
#pragma unroll
  for (int g = 0; g < 4; ++g)
#pragma unroll
    for (int r = 0; r < 4; ++r) { minv[g][r] = 3.4e38f; mini[g][r] = 0; }

  // ---- K loop over 64 code-tiles of 16 codes ----
  // D layout (verified m89/m91): col = lane&15 (code), row = q*4+reg (position).
#pragma unroll 4
  for (int t = 0; t < 64; ++t) {
    uint4 bu0 = ws_frag[t * 128 + lane];        // k  0..31
    uint4 bu1 = ws_frag[t * 128 + 64 + lane];   // k 32..63
    float nrm = ws_norm[t * 16 + col];
    union { uint4 q4; v8s v; } bb0, bb1;
    bb0.q4 = bu0; bb1.q4 = bu1;
    int code = t * 16 + col;
#pragma unroll
    for (int g = 0; g < 4; ++g) {
      v4f acc = {0.f, 0.f, 0.f, 0.f};
      acc = __builtin_amdgcn_mfma_f32_16x16x32_bf16(afrag[g][0], bb0.v, acc, 0, 0, 0);
      acc = __builtin_amdgcn_mfma_f32_16x16x32_bf16(afrag[g][1], bb1.v, acc, 0, 0, 0);
#pragma unroll
      for (int r = 0; r < 4; ++r) {
        float d = fmaf(-2.f, acc[r], nrm);   // ||e||^2 - 2 z.e
        if (d < minv[g][r]) { minv[g][r] = d; mini[g][r] = code; }
      }
    }
  }

  // ---- reduce across the 16 cols (same positions, disjoint code sets) ----
  // tie -> lower index, matching jnp.argmin first-wins.
#pragma unroll
  for (int off = 1; off < 16; off <<= 1) {
#pragma unroll
    for (int g = 0; g < 4; ++g)
#pragma unroll
      for (int r = 0; r < 4; ++r) {
        float ov = __shfl_xor(minv[g][r], off, 64);
        int   oi = __shfl_xor(mini[g][r], off, 64);
        if (ov < minv[g][r] || (ov == minv[g][r] && oi < mini[g][r])) {
          minv[g][r] = ov; mini[g][r] = oi;
        }
      }
  }
  if (col == 0) {
#pragma unroll
    for (int g = 0; g < 4; ++g)
#pragma unroll
      for (int r = 0; r < 4; ++r)
        idx_lds[wave * 64 + g * 16 + q * 4 + r] = mini[g][r];
  }
  __syncthreads();

  // ---- epilogue: z_q scatter (exact fp32 embed) + loss ----
  float lacc = 0.f;
  {
    const int w  = tid & 63;
    const int cq = tid >> 6;     // 0..3 -> 16 channels each
    const int c0 = cq * 16;
#pragma unroll
    for (int hh = 0; hh < 4; ++hh) {
      int p   = hh * 64 + w;
      int idx = idx_lds[p];
      const float4* erow = (const float4*)(embed + idx * C_DIM);
      float* ob = out + b * CHW + (h0 + hh) * 64 + w;
#pragma unroll
      for (int j = 0; j < 4; ++j) {
        int c = c0 + j * 4;
        float4 ev = erow[c >> 2];
        float4 zv = *(const float4*)&z_lds[p * ZPAD + c];
        ob[(c + 0) * HW] = ev.x;
        ob[(c + 1) * HW] = ev.y;
        ob[(c + 2) * HW] = ev.z;
        ob[(c + 3) * HW] = ev.w;
        float dx = ev.x - zv.x, dy = ev.y - zv.y;
        float dz = ev.z - zv.z, dw = ev.w - zv.w;
        lacc += dx * dx + dy * dy + dz * dz + dw * dw;
      }
    }
  }
#pragma unroll
  for (int off = 32; off >= 1; off >>= 1) lacc += __shfl_xor(lacc, off, 64);
  if (lane == 0) wl[wave] = lacc;
  __syncthreads();
  if (tid == 0) {
    float s = (wl[0] + wl[1]) + (wl[2] + wl[3]);
    atomicAdd(out + OUT_ELEMS, s * LOSS_SCALE);  // zeroed by vq_setup, same stream
  }
}

extern "C" void kernel_launch(void* const* d_in, const int* in_sizes, int n_in,
                              void* d_out, int out_size, void* d_ws, size_t ws_size,
                              hipStream_t stream) {
  const float* z     = (const float*)d_in[0];
  const float* embed = (const float*)d_in[1];
  float* out = (float*)d_out;
  // d_ws layout: [0,4096) norms fp32 (1024 used), [4096, 4096+131072) bf16 frag table
  float* ws_norm = (float*)d_ws;
  uint4* ws_frag = (uint4*)((char*)d_ws + 4096);

  vq_setup<<<32, 256, 0, stream>>>(embed, ws_norm, ws_frag, out + OUT_ELEMS);
  vq_main<<<256, 256, 0, stream>>>(z, embed, ws_norm, (const uint4*)ws_frag, out);
}

// Round 2
// 101.092 us; speedup vs baseline: 1.0969x; 1.0969x over previous
//
#include <hip/hip_runtime.h>

// VQ-VAE vector quantizer, MI355X gfx950.
// z: [16,64,64,64] fp32, embed: [1024,64] fp32.
// out: z_q_st [16,64,64,64] fp32, then loss scalar.
//
// R1: distances via bf16 MFMA, fused argmin, exact-fp32 epilogue.  46 us main,
//     but 1 block/CU (69KB LDS + launch_bounds(256,1)) -> latency-bound
//     (MfmaUtil 6%, VALUBusy 19%, Occupancy 9%).
// R2: 1024 blocks x 256 thr; block = 64 positions (one (b,h) row); 4 waves
//     K-split (256 codes each) + LDS argmin merge. No z LDS tile (A-frags
//     gathered from L3-hot z; loss re-reads z coalesced). LDS ~2.6KB,
//     VGPR-bound occupancy: 16 waves/CU.

#define K_CODES   1024
#define C_DIM     64
#define HW        4096
#define CHW       262144
#define OUT_ELEMS 4194304
#define LOSS_SCALE (1.25f / 4194304.0f)

typedef short v8s __attribute__((ext_vector_type(8)));
typedef float v4f __attribute__((ext_vector_type(4)));

__device__ __forceinline__ unsigned short f2bf(float x) {
  // round-to-nearest-even fp32 -> bf16 (inputs finite)
  unsigned int u = __float_as_uint(x);
  return (unsigned short)((u + 0x7FFFu + ((u >> 16) & 1u)) >> 16);
}

// ---------------------------------------------------------------------------
// Setup kernel: 32 blocks x 256 threads (8192 threads).
//  - packs embed into bf16 B-fragment order: for code-tile t (16 codes),
//    k-half h, lane l (col=l&15,q=l>>4): 16B chunk = embed[t*16+col][h*32+q*8..+7]
//    stored at ws_frag[t*128 + h*64 + l]  -> main-loop loads are coalesced.
//  - threads 0..1023: ws_norm[k] = ||embed[k]||^2 in fp32.
//  - thread 0: zero the loss accumulator (d_out is poisoned 0xAA pre-launch).
// ---------------------------------------------------------------------------
__global__ __launch_bounds__(256) void vq_setup(const float* __restrict__ embed,
                                                float* __restrict__ ws_norm,
                                                uint4* __restrict__ ws_frag,
                                                float* __restrict__ out_loss) {
  int id = blockIdx.x * 256 + threadIdx.x;   // 0..8191
  int t   = id >> 7;        // code tile 0..63
  int r   = id & 127;
  int h   = r >> 6;         // k-half 0..1
  int l   = r & 63;         // lane
  int col = l & 15;
  int q   = l >> 4;
  int code = t * 16 + col;
  const float* src = embed + code * C_DIM + h * 32 + q * 8;
  float4 f0 = ((const float4*)src)[0];
  float4 f1 = ((const float4*)src)[1];
  union { unsigned short u[8]; uint4 q4; } pk;
  pk.u[0] = f2bf(f0.x); pk.u[1] = f2bf(f0.y); pk.u[2] = f2bf(f0.z); pk.u[3] = f2bf(f0.w);
  pk.u[4] = f2bf(f1.x); pk.u[5] = f2bf(f1.y); pk.u[6] = f2bf(f1.z); pk.u[7] = f2bf(f1.w);
  ws_frag[id] = pk.q4;

  if (id < K_CODES) {
    const float4* row = (const float4*)(embed + id * C_DIM);
    float s = 0.f;
#pragma unroll
    for (int i = 0; i < 16; ++i) {
      float4 v = row[i];
      s += v.x * v.x + v.y * v.y + v.z * v.z + v.w * v.w;
    }
    ws_norm[id] = s;
  }
  if (id == 0) *out_loss = 0.f;
}

// ---------------------------------------------------------------------------
// Main kernel: 1024 blocks x 256 threads (4 waves).
// Block = 64 positions: b = blk>>6, h = blk&63, w = 0..63.
// Each wave computes argmin over its 256-code slice for ALL 64 positions;
// waves merge via LDS (tie -> lower wave = lower code, first-occurrence).
// ---------------------------------------------------------------------------
__global__ __launch_bounds__(256, 4) void vq_main(const float* __restrict__ z,
                                                  const float* __restrict__ embed,
                                                  const float* __restrict__ ws_norm,
                                                  const uint4* __restrict__ ws_frag,
                                                  float* __restrict__ out) {
  __shared__ float rminv[4][64];
  __shared__ int   rmini[4][64];
  __shared__ int   idx_lds[64];
  __shared__ float wl[4];

  const int tid  = threadIdx.x;
  const int lane = tid & 63;
  const int wave = tid >> 6;
  const int col  = lane & 15;
  const int q    = lane >> 4;
  const int b    = blockIdx.x >> 6;
  const int h    = blockIdx.x & 63;
  const float* zb = z + b * CHW + h * 64;   // + c*HW + w

  // ---- build A-frags (z as bf16) straight from global (L3-hot) ----
  // A layout: lane m=lane&15 holds A[m][q*8+j]; hf selects k-half (c += 32).
  v8s afrag[4][2];
#pragma unroll
  for (int g = 0; g < 4; ++g) {
    const int w0 = g * 16 + col;
#pragma unroll
    for (int hf = 0; hf < 2; ++hf) {
      const float* src = zb + (hf * 32 + q * 8) * HW + w0;
      union { v8s v; unsigned short u[8]; } pk;
#pragma unroll
      for (int j = 0; j < 8; ++j) pk.u[j] = f2bf(src[j * HW]);
      afrag[g][hf] = pk.v;
    }
  }

  float minv[4][4];
  int   mini[4][4];
#pragma unroll
  for (int g = 0; g < 4; ++g)
#pragma unroll
    for (int r = 0; r < 4; ++r) { minv[g][r] = 3.4e38f; mini[g][r] = 0; }

  // ---- K loop: this wave's 16 code-tiles (256 codes) ----
  // D layout (verified m89/m91): col = lane&15 (code), row = q*4+reg (position).
  const int t0 = wave * 16;
#pragma unroll 4
  for (int tt = 0; tt < 16; ++tt) {
    const int t = t0 + tt;
    uint4 bu0 = ws_frag[t * 128 + lane];        // k  0..31
    uint4 bu1 = ws_frag[t * 128 + 64 + lane];   // k 32..63
    float nrm = ws_norm[t * 16 + col];
    union { uint4 q4; v8s v; } bb0, bb1;
    bb0.q4 = bu0; bb1.q4 = bu1;
    int code = t * 16 + col;
#pragma unroll
    for (int g = 0; g < 4; ++g) {
      v4f acc = {0.f, 0.f, 0.f, 0.f};
      acc = __builtin_amdgcn_mfma_f32_16x16x32_bf16(afrag[g][0], bb0.v, acc, 0, 0, 0);
      acc = __builtin_amdgcn_mfma_f32_16x16x32_bf16(afrag[g][1], bb1.v, acc, 0, 0, 0);
#pragma unroll
      for (int r = 0; r < 4; ++r) {
        float d = fmaf(-2.f, acc[r], nrm);   // ||e||^2 - 2 z.e
        if (d < minv[g][r]) { minv[g][r] = d; mini[g][r] = code; }
      }
    }
  }

  // ---- reduce across the 16 cols (disjoint code sets; tie -> lower index) ----
#pragma unroll
  for (int off = 1; off < 16; off <<= 1) {
#pragma unroll
    for (int g = 0; g < 4; ++g)
#pragma unroll
      for (int r = 0; r < 4; ++r) {
        float ov = __shfl_xor(minv[g][r], off, 64);
        int   oi = __shfl_xor(mini[g][r], off, 64);
        if (ov < minv[g][r] || (ov == minv[g][r] && oi < mini[g][r])) {
          minv[g][r] = ov; mini[g][r] = oi;
        }
      }
  }
  if (col == 0) {
#pragma unroll
    for (int g = 0; g < 4; ++g)
#pragma unroll
      for (int r = 0; r < 4; ++r) {
        rminv[wave][g * 16 + q * 4 + r] = minv[g][r];
        rmini[wave][g * 16 + q * 4 + r] = mini[g][r];
      }
  }
  __syncthreads();

  // ---- merge across waves (wave wv covers codes [wv*256,(wv+1)*256):
  //      ascending, so strict < keeps the lowest index on ties) ----
  if (tid < 64) {
    float bv = rminv[0][tid];
    int   bi = rmini[0][tid];
#pragma unroll
    for (int wv = 1; wv < 4; ++wv) {
      float v = rminv[wv][tid];
      int   i = rmini[wv][tid];
      if (v < bv) { bv = v; bi = i; }
    }
    idx_lds[tid] = bi;
  }
  __syncthreads();

  // ---- epilogue: z_q scatter (exact fp32 embed) + loss (z re-read, L3-hot) ----
  float lacc = 0.f;
  {
    const int w  = tid & 63;
    const int cq = tid >> 6;     // 0..3 -> 16 channels each
    const int idx = idx_lds[w];
    const float4* erow = (const float4*)(embed + idx * C_DIM);
    float* ob = out + b * CHW + h * 64 + w;
    const float* zp = zb + w;
#pragma unroll
    for (int j = 0; j < 4; ++j) {
      int c = cq * 16 + j * 4;
      float4 ev = erow[c >> 2];
      ob[(c + 0) * HW] = ev.x;
      ob[(c + 1) * HW] = ev.y;
      ob[(c + 2) * HW] = ev.z;
      ob[(c + 3) * HW] = ev.w;
      float dx = ev.x - zp[(c + 0) * HW];
      float dy = ev.y - zp[(c + 1) * HW];
      float dz = ev.z - zp[(c + 2) * HW];
      float dw = ev.w - zp[(c + 3) * HW];
      lacc += dx * dx + dy * dy + dz * dz + dw * dw;
    }
  }
#pragma unroll
  for (int off = 32; off >= 1; off >>= 1) lacc += __shfl_xor(lacc, off, 64);
  if (lane == 0) wl[wave] = lacc;
  __syncthreads();
  if (tid == 0) {
    float s = (wl[0] + wl[1]) + (wl[2] + wl[3]);
    atomicAdd(out + OUT_ELEMS, s * LOSS_SCALE);  // zeroed by vq_setup, same stream
  }
}

extern "C" void kernel_launch(void* const* d_in, const int* in_sizes, int n_in,
                              void* d_out, int out_size, void* d_ws, size_t ws_size,
                              hipStream_t stream) {
  const float* z     = (const float*)d_in[0];
  const float* embed = (const float*)d_in[1];
  float* out = (float*)d_out;
  // d_ws layout: [0,4096) norms fp32 (1024 used), [4096, 4096+131072) bf16 frag table
  float* ws_norm = (float*)d_ws;
  uint4* ws_frag = (uint4*)((char*)d_ws + 4096);

  vq_setup<<<32, 256, 0, stream>>>(embed, ws_norm, ws_frag, out + OUT_ELEMS);
  vq_main<<<1024, 256, 0, stream>>>(z, embed, ws_norm, (const uint4*)ws_frag, out);
}

// Round 3
// 97.226 us; speedup vs baseline: 1.1405x; 1.0398x over previous
//
#include <hip/hip_runtime.h>
#include <hip/hip_bf16.h>

// VQ-VAE vector quantizer, MI355X gfx950.
// z: [16,64,64,64] fp32, embed: [1024,64] fp32.
// out: z_q_st [16,64,64,64] fp32, then loss scalar.
//
// R1: bf16-MFMA distances + fused argmin. 46 us main; 1 block/CU -> latency.
// R2: 1024 blocks, 4-wave K-split, no z LDS tile. main left top-5 (<43 us);
//     total 101 us (harness poison/restore floor ~65-70 us).
// R3: packed (dist|code) u32 argmin -> v_min_u32 everywhere:
//       - K-loop update: fma + v_and_or_b32 + v_min_u32 (3 VALU/elem)
//       - col-reduce: 64 bpermute + 64 min (was 128 bperm + ~384 VALU)
//       - wave-merge: 3 mins; tie->lower code automatic (codes ascend with wave)
//     norms stored pre-biased (+1.0) so keys are positive floats (monotone bits).
//     A-frag bf16 pack via hw cvt (__float22bfloat162_rn).

#define K_CODES   1024
#define C_DIM     64
#define HW        4096
#define CHW       262144
#define OUT_ELEMS 4194304
#define LOSS_SCALE (1.25f / 4194304.0f)
#define KEY_MASK  0xFFFFFC00u   // keep exponent + top 13 mantissa bits

typedef short v8s __attribute__((ext_vector_type(8)));
typedef float v4f __attribute__((ext_vector_type(4)));

__device__ __forceinline__ unsigned short f2bf(float x) {
  // round-to-nearest-even fp32 -> bf16 (inputs finite)
  unsigned int u = __float_as_uint(x);
  return (unsigned short)((u + 0x7FFFu + ((u >> 16) & 1u)) >> 16);
}

__device__ __forceinline__ ushort2 f2bf2(float x, float y) {
  union { __hip_bfloat162 h; ushort2 u; } c;
  c.h = __float22bfloat162_rn(make_float2(x, y));
  return c.u;
}

// ---------------------------------------------------------------------------
// Setup kernel: 32 blocks x 256 threads (8192 threads).
//  - packs embed into bf16 B-fragment order: for code-tile t (16 codes),
//    k-half h, lane l (col=l&15,q=l>>4): 16B chunk = embed[t*16+col][h*32+q*8..+7]
//    stored at ws_frag[t*128 + h*64 + l]  -> main-loop loads are coalesced.
//  - threads 0..1023: ws_norm[k] = ||embed[k]||^2 + 1.0 (key bias) in fp32.
//  - thread 0: zero the loss accumulator (d_out is poisoned 0xAA pre-launch).
// ---------------------------------------------------------------------------
__global__ __launch_bounds__(256) void vq_setup(const float* __restrict__ embed,
                                                float* __restrict__ ws_norm,
                                                uint4* __restrict__ ws_frag,
                                                float* __restrict__ out_loss) {
  int id = blockIdx.x * 256 + threadIdx.x;   // 0..8191
  int t   = id >> 7;        // code tile 0..63
  int r   = id & 127;
  int h   = r >> 6;         // k-half 0..1
  int l   = r & 63;         // lane
  int col = l & 15;
  int q   = l >> 4;
  int code = t * 16 + col;
  const float* src = embed + code * C_DIM + h * 32 + q * 8;
  float4 f0 = ((const float4*)src)[0];
  float4 f1 = ((const float4*)src)[1];
  union { unsigned short u[8]; uint4 q4; } pk;
  pk.u[0] = f2bf(f0.x); pk.u[1] = f2bf(f0.y); pk.u[2] = f2bf(f0.z); pk.u[3] = f2bf(f0.w);
  pk.u[4] = f2bf(f1.x); pk.u[5] = f2bf(f1.y); pk.u[6] = f2bf(f1.z); pk.u[7] = f2bf(f1.w);
  ws_frag[id] = pk.q4;

  if (id < K_CODES) {
    const float4* row = (const float4*)(embed + id * C_DIM);
    float s = 0.f;
#pragma unroll
    for (int i = 0; i < 16; ++i) {
      float4 v = row[i];
      s += v.x * v.x + v.y * v.y + v.z * v.z + v.w * v.w;
    }
    ws_norm[id] = s + 1.0f;   // pre-biased: keys = dist+1 > 0
  }
  if (id == 0) *out_loss = 0.f;
}

// ---------------------------------------------------------------------------
// Main kernel: 1024 blocks x 256 threads (4 waves).
// Block = 64 positions: b = blk>>6, h = blk&63, w = 0..63.
// Each wave: argmin (packed key) over its 256-code slice for all 64 positions;
// waves merge via LDS u32 min (tie -> lower code automatically).
// ---------------------------------------------------------------------------
__global__ __launch_bounds__(256, 4) void vq_main(const float* __restrict__ z,
                                                  const float* __restrict__ embed,
                                                  const float* __restrict__ ws_norm,
                                                  const uint4* __restrict__ ws_frag,
                                                  float* __restrict__ out) {
  __shared__ unsigned int rmin[4][64];
  __shared__ int idx_lds[64];
  __shared__ float wl[4];

  const int tid  = threadIdx.x;
  const int lane = tid & 63;
  const int wave = tid >> 6;
  const int col  = lane & 15;
  const int q    = lane >> 4;
  const int b    = blockIdx.x >> 6;
  const int h    = blockIdx.x & 63;
  const float* zb = z + b * CHW + h * 64;   // + c*HW + w

  // ---- build A-frags (z as bf16) straight from global (L3-hot) ----
  // A layout: lane m=lane&15 holds A[m][q*8+j]; hf selects k-half (c += 32).
  v8s afrag[4][2];
#pragma unroll
  for (int g = 0; g < 4; ++g) {
    const int w0 = g * 16 + col;
#pragma unroll
    for (int hf = 0; hf < 2; ++hf) {
      const float* src = zb + (hf * 32 + q * 8) * HW + w0;
      float f[8];
#pragma unroll
      for (int j = 0; j < 8; ++j) f[j] = src[j * HW];
      union { v8s v; ushort2 u2[4]; } pk;
#pragma unroll
      for (int j = 0; j < 4; ++j) pk.u2[j] = f2bf2(f[2 * j], f[2 * j + 1]);
      afrag[g][hf] = pk.v;
    }
  }

  unsigned int umin[4][4];
#pragma unroll
  for (int g = 0; g < 4; ++g)
#pragma unroll
    for (int r = 0; r < 4; ++r) umin[g][r] = 0xFFFFFFFFu;

  // ---- K loop: this wave's 16 code-tiles (256 codes) ----
  // D layout (verified m89/m91): col = lane&15 (code), row = q*4+reg (position).
  const int t0 = wave * 16;
#pragma unroll 4
  for (int tt = 0; tt < 16; ++tt) {
    const int t = t0 + tt;
    uint4 bu0 = ws_frag[t * 128 + lane];        // k  0..31
    uint4 bu1 = ws_frag[t * 128 + 64 + lane];   // k 32..63
    float nrm1 = ws_norm[t * 16 + col];         // ||e||^2 + 1
    union { uint4 q4; v8s v; } bb0, bb1;
    bb0.q4 = bu0; bb1.q4 = bu1;
    unsigned int code = (unsigned int)(t * 16 + col);
#pragma unroll
    for (int g = 0; g < 4; ++g) {
      v4f acc = {0.f, 0.f, 0.f, 0.f};
      acc = __builtin_amdgcn_mfma_f32_16x16x32_bf16(afrag[g][0], bb0.v, acc, 0, 0, 0);
      acc = __builtin_amdgcn_mfma_f32_16x16x32_bf16(afrag[g][1], bb1.v, acc, 0, 0, 0);
#pragma unroll
      for (int r = 0; r < 4; ++r) {
        float key = fmaf(-2.f, acc[r], nrm1);          // dist + 1 > 0
        unsigned int u = (__float_as_uint(key) & KEY_MASK) | code;  // v_and_or_b32
        umin[g][r] = min(umin[g][r], u);               // v_min_u32
      }
    }
  }

  // ---- reduce across the 16 cols: pure u32 min (tie -> lower code) ----
#pragma unroll
  for (int off = 1; off < 16; off <<= 1) {
#pragma unroll
    for (int g = 0; g < 4; ++g)
#pragma unroll
      for (int r = 0; r < 4; ++r) {
        unsigned int ov = (unsigned int)__shfl_xor((int)umin[g][r], off, 64);
        umin[g][r] = min(umin[g][r], ov);
      }
  }
  if (col == 0) {
#pragma unroll
    for (int g = 0; g < 4; ++g)
#pragma unroll
      for (int r = 0; r < 4; ++r)
        rmin[wave][g * 16 + q * 4 + r] = umin[g][r];
  }
  __syncthreads();

  // ---- merge across waves (codes ascend with wave; u32 min keeps lowest) ----
  if (tid < 64) {
    unsigned int bv = min(min(rmin[0][tid], rmin[1][tid]),
                          min(rmin[2][tid], rmin[3][tid]));
    idx_lds[tid] = (int)(bv & 1023u);
  }
  __syncthreads();

  // ---- epilogue: z_q scatter (exact fp32 embed) + loss (z re-read, L3-hot) ----
  float lacc = 0.f;
  {
    const int w  = tid & 63;
    const int cq = tid >> 6;     // 0..3 -> 16 channels each
    const int idx = idx_lds[w];
    const float4* erow = (const float4*)(embed + idx * C_DIM);
    float* ob = out + b * CHW + h * 64 + w;
    const float* zp = zb + w;
#pragma unroll
    for (int j = 0; j < 4; ++j) {
      int c = cq * 16 + j * 4;
      float4 ev = erow[c >> 2];
      ob[(c + 0) * HW] = ev.x;
      ob[(c + 1) * HW] = ev.y;
      ob[(c + 2) * HW] = ev.z;
      ob[(c + 3) * HW] = ev.w;
      float dx = ev.x - zp[(c + 0) * HW];
      float dy = ev.y - zp[(c + 1) * HW];
      float dz = ev.z - zp[(c + 2) * HW];
      float dw = ev.w - zp[(c + 3) * HW];
      lacc += dx * dx + dy * dy + dz * dz + dw * dw;
    }
  }
#pragma unroll
  for (int off = 32; off >= 1; off >>= 1) lacc += __shfl_xor(lacc, off, 64);
  if (lane == 0) wl[wave] = lacc;
  __syncthreads();
  if (tid == 0) {
    float s = (wl[0] + wl[1]) + (wl[2] + wl[3]);
    atomicAdd(out + OUT_ELEMS, s * LOSS_SCALE);  // zeroed by vq_setup, same stream
  }
}

extern "C" void kernel_launch(void* const* d_in, const int* in_sizes, int n_in,
                              void* d_out, int out_size, void* d_ws, size_t ws_size,
                              hipStream_t stream) {
  const float* z     = (const float*)d_in[0];
  const float* embed = (const float*)d_in[1];
  float* out = (float*)d_out;
  // d_ws layout: [0,4096) biased norms fp32 (1024 used), [4096, +131072) bf16 frags
  float* ws_norm = (float*)d_ws;
  uint4* ws_frag = (uint4*)((char*)d_ws + 4096);

  vq_setup<<<32, 256, 0, stream>>>(embed, ws_norm, ws_frag, out + OUT_ELEMS);
  vq_main<<<1024, 256, 0, stream>>>(z, embed, ws_norm, (const uint4*)ws_frag, out);
}